// Round 8
// baseline (95.129 us; speedup 1.0000x reference)
//
#include <hip/hip_runtime.h>

typedef __bf16 bf16x8 __attribute__((ext_vector_type(8)));
typedef float  f32x4  __attribute__((ext_vector_type(4)));

#define HD     512            // H*D
#define NITEMS 512            // 4 tt-levels x 128 (b,h) groups
#define C1     8.6316745750310966e-05f  // ALPHA/1024
#define C2     0.12751793f              // ALPHA*log2(e)

__device__ __forceinline__ unsigned int cvt_pk_bf16(float lo, float hi) {
    unsigned int r;
    asm("v_cvt_pk_bf16_f32 %0, %1, %2" : "=v"(r) : "v"(lo), "v"(hi));
    return r;
}

union PA8 { unsigned int u[4]; bf16x8 v; };

// Persistent blocks, dynamic LPT queue over 256-row tile items (tt-major,
// biggest first). 8 waves x 32 q-rows (two 16-row subtiles share every LDS
// fragment read). KV chunk 64, ping-pong LDS (2 x 32KB), 1 barrier/chunk,
// reg-prefetch 2 ahead, swapped QK^T -> in-register P exchange via bpermute.
__global__ __launch_bounds__(512)
void hstu_attn_fwd(const float* __restrict__ Q, const float* __restrict__ K,
                   const float* __restrict__ V,
                   const int* __restrict__ offs,
                   const int* __restrict__ ntgt,
                   float* __restrict__ Out,
                   unsigned int* __restrict__ ctr)
{
    __shared__ __align__(16) char smem[65536];
    __shared__ int s_item;

    const int tid = threadIdx.x;
    const int w = tid >> 6, lane = tid & 63, l15 = lane & 15, g8 = lane >> 4;

    // staging decode
    const int kj0 = tid >> 4, kd8 = tid & 15;   // K: row kj0(+32s), 16B unit kd8
    const int vg0 = tid >> 7, vd  = tid & 127;  // V: group vg0(+4s), column vd

    // bpermute addresses for the P exchange (bytes = lane*4)
    const int addrA = ((((g8 & 1) << 5) + l15) << 2);
    const int addrB = addrA + 64;

    for (;;) {
        __syncthreads();
        if (tid == 0) s_item = (int)atomicAdd(ctr, 1u);
        __syncthreads();
        const int it = s_item;
        if (it >= NITEMS) break;

        const int tt = it >> 7;            // 0..3, big tiles first
        const int G  = it & 127;
        const int b  = G >> 2;
        const int h  = G & 3;

        const int s0 = offs[b];
        const int L  = offs[b + 1] - s0;
        const int T  = (L + 255) >> 8;     // 256-row tiles
        const int t  = T - 1 - tt;
        if (t < 0) continue;
        const int cap = L - ntgt[b];

        const float* Kb = K + (size_t)s0 * HD + h * 128;
        const float* Vb = V + (size_t)s0 * HD + h * 128;

        const int r0  = t << 8;
        const int wr0 = r0 + (w << 5);     // wave owns rows wr0..wr0+31

        int wave_jmax;
        if (wr0 >= L)            wave_jmax = 0;
        else if (wr0 + 32 > cap) wave_jmax = L;
        else                     wave_jmax = wr0 + 32;

        const int jmax = (r0 + 256 > cap) ? L : (r0 + 256);
        const int nch  = (jmax + 63) >> 6;

        // ---- Q fragments (B-operand of swapped QK^T), two subtiles ----
        bf16x8 qa[2][4];
#pragma unroll
        for (int u = 0; u < 2; ++u) {
            int qr = wr0 + u * 16 + l15; if (qr > L - 1) qr = L - 1;
            const float* qp = Q + (size_t)(s0 + qr) * HD + h * 128 + g8 * 8;
#pragma unroll
            for (int kc = 0; kc < 4; ++kc) {
                f32x4 x0 = *(const f32x4*)(qp + kc * 32);
                f32x4 x1 = *(const f32x4*)(qp + kc * 32 + 4);
                bf16x8 a;
#pragma unroll
                for (int e = 0; e < 4; ++e) { a[e] = (__bf16)x0[e]; a[e + 4] = (__bf16)x1[e]; }
                qa[u][kc] = a;
            }
        }

        f32x4 oacc[2][8];
#pragma unroll
        for (int u = 0; u < 2; ++u)
#pragma unroll
            for (int i = 0; i < 8; ++i) oacc[u][i] = f32x4{0.f, 0.f, 0.f, 0.f};

        f32x4 kreg[4];
        float vreg[16];

        auto load_chunk = [&](int j0c) {
#pragma unroll
            for (int s = 0; s < 2; ++s) {
                int j = j0c + kj0 + s * 32; if (j > L - 1) j = L - 1;
                const float* p = Kb + (size_t)j * HD + kd8 * 8;
                kreg[s * 2]     = *(const f32x4*)p;
                kreg[s * 2 + 1] = *(const f32x4*)(p + 4);
            }
#pragma unroll
            for (int s = 0; s < 2; ++s) {
                const int gg = vg0 + s * 4;
#pragma unroll
                for (int e = 0; e < 8; ++e) {
                    int j = j0c + gg * 8 + e; if (j > L - 1) j = L - 1;
                    vreg[s * 8 + e] = Vb[(size_t)j * HD + vd];
                }
            }
        };
        auto write_buf = [&](int p) {
            char* wK = smem + p * 32768;
            char* wV = wK + 16384;
#pragma unroll
            for (int s = 0; s < 2; ++s) {
                const int j = kj0 + s * 32;
                bf16x8 kb;
#pragma unroll
                for (int e = 0; e < 4; ++e) { kb[e] = (__bf16)kreg[s*2][e]; kb[e+4] = (__bf16)kreg[s*2+1][e]; }
                *(bf16x8*)(wK + ((j * 256 + kd8 * 16) ^ ((j & 7) << 4))) = kb;
            }
#pragma unroll
            for (int s = 0; s < 2; ++s) {
                bf16x8 vbw;
#pragma unroll
                for (int e = 0; e < 8; ++e) vbw[e] = (__bf16)vreg[s * 8 + e];
                *(bf16x8*)(wV + (vg0 + s * 4) * 2048 + vd * 16) = vbw;
            }
        };

        // prologue: chunk0 -> buf0; prefetch chunk1
        load_chunk(0);
        write_buf(0);
        if (nch > 1) load_chunk(64);
        __syncthreads();

        for (int c = 0; c < nch; ++c) {
            const int j0 = c << 6;
            const char* bK = smem + (c & 1) * 32768;
            const char* bV = bK + 16384;

            if (j0 < wave_jmax) {
                unsigned int pk[2][4][2];
                __builtin_amdgcn_s_setprio(1);
#pragma unroll
                for (int jt = 0; jt < 4; ++jt) {
                    const int jl = (jt << 4) + l15;
                    bf16x8 kb[4];
#pragma unroll
                    for (int kc = 0; kc < 4; ++kc) {
                        const int byt = (jl * 256 + (kc * 32 + g8 * 8) * 2) ^ ((jl & 7) << 4);
                        kb[kc] = *(const bf16x8*)(bK + byt);
                    }
#pragma unroll
                    for (int u = 0; u < 2; ++u) {
                        f32x4 sacc = f32x4{0.f, 0.f, 0.f, 0.f};
#pragma unroll
                        for (int kc = 0; kc < 4; ++kc)
                            sacc = __builtin_amdgcn_mfma_f32_16x16x32_bf16(kb[kc], qa[u][kc], sacc, 0, 0, 0);
                        // silu + mask: kv = j0 + 16*jt + 4*g8 + r, q = qrow
                        const int qrow = wr0 + u * 16 + l15;
#pragma unroll
                        for (int r = 0; r < 4; ++r) {
                            const int gj = j0 + (jt << 4) + (g8 << 2) + r;
                            const float e2 = __builtin_amdgcn_exp2f(-(sacc[r] * C2));
                            float p = sacc[r] * C1 * __builtin_amdgcn_rcpf(1.f + e2);
                            const bool valid = (gj < L) && ((gj <= qrow) || (qrow >= cap));
                            sacc[r] = valid ? p : 0.f;
                        }
                        pk[u][jt][0] = cvt_pk_bf16(sacc[0], sacc[1]);
                        pk[u][jt][1] = cvt_pk_bf16(sacc[2], sacc[3]);
                    }
                }
                // ---- in-register P exchange + PV (vb shared across subtiles) ----
#pragma unroll
                for (int kk = 0; kk < 2; ++kk) {
                    PA8 pa[2];
#pragma unroll
                    for (int u = 0; u < 2; ++u)
#pragma unroll
                    for (int hp = 0; hp < 2; ++hp) {
                        const int ad = hp ? addrB : addrA;
#pragma unroll
                        for (int pr = 0; pr < 2; ++pr) {
                            const int ca = __builtin_amdgcn_ds_bpermute(ad, (int)pk[u][2*kk][pr]);
                            const int cb = __builtin_amdgcn_ds_bpermute(ad, (int)pk[u][2*kk+1][pr]);
                            pa[u].u[hp * 2 + pr] = (g8 < 2) ? (unsigned int)ca : (unsigned int)cb;
                        }
                    }
#pragma unroll
                    for (int dt = 0; dt < 8; ++dt) {
                        bf16x8 vb = *(const bf16x8*)(bV + (kk * 4 + g8) * 2048 + ((dt << 4) + l15) * 16);
                        oacc[0][dt] = __builtin_amdgcn_mfma_f32_16x16x32_bf16(pa[0].v, vb, oacc[0][dt], 0, 0, 0);
                        oacc[1][dt] = __builtin_amdgcn_mfma_f32_16x16x32_bf16(pa[1].v, vb, oacc[1][dt], 0, 0, 0);
                    }
                }
                __builtin_amdgcn_s_setprio(0);
            }

            if (c + 1 < nch) write_buf((c + 1) & 1);
            if (c + 2 < nch) load_chunk((c + 2) << 6);
            __syncthreads();
        }

        // ---- write O (f32): row wr0+16u+(g8<<2)+r, col dt*16+l15 ----
#pragma unroll
        for (int u = 0; u < 2; ++u)
#pragma unroll
        for (int r = 0; r < 4; ++r) {
            const int gir = wr0 + u * 16 + (g8 << 2) + r;
            if (gir < L) {
                float* op = Out + (size_t)(s0 + gir) * HD + h * 128 + l15;
#pragma unroll
                for (int dt = 0; dt < 8; ++dt) op[dt << 4] = oacc[u][dt][r];
            }
        }
    }
}

extern "C" void kernel_launch(void* const* d_in, const int* in_sizes, int n_in,
                              void* d_out, int out_size, void* d_ws, size_t ws_size,
                              hipStream_t stream) {
    (void)in_sizes; (void)n_in; (void)ws_size; (void)out_size;
    const float* q = (const float*)d_in[0];
    const float* k = (const float*)d_in[1];
    const float* v = (const float*)d_in[2];
    const int* offs = (const int*)d_in[3];
    const int* ntgt = (const int*)d_in[4];
    float* out = (float*)d_out;
    unsigned int* ctr = (unsigned int*)d_ws;
    hipMemsetAsync(ctr, 0, 4, stream);
    dim3 grid(512, 1, 1), block(512, 1, 1);
    hipLaunchKernelGGL(hstu_attn_fwd, grid, block, 0, stream, q, k, v, offs, ntgt, out, ctr);
}